// Round 6
// baseline (326.132 us; speedup 1.0000x reference)
//
#include <hip/hip_runtime.h>
#include <hip/hip_bf16.h>

#define NB  8
#define NC  256
#define NCK 64
#define SEQ 2048
#define MB_ ((size_t)1 << 20)

typedef unsigned short u16;
typedef short bfrag8 __attribute__((ext_vector_type(8)));   // 8 bf16 (4 VGPRs)
typedef float ffrag4 __attribute__((ext_vector_type(4)));   // 4 fp32 acc

#define MFMA16(a, b, c) __builtin_amdgcn_mfma_f32_16x16x32_bf16((a), (b), (c), 0, 0, 0)

static __device__ __forceinline__ u16 f2bf(float f) {
  return __builtin_bit_cast(u16, (__bf16)f);  // RNE
}
static __device__ __forceinline__ float bf2f(u16 u) {
  unsigned v = (unsigned)u << 16;
  return __builtin_bit_cast(float, v);
}

// ---------- W fp32 -> bf16 hi/lo; last block zeroes ssum/sqsum ----------
__global__ __launch_bounds__(256) void wconv_kernel(
    const float* __restrict__ Wq, const float* __restrict__ Wv,
    const float* __restrict__ Wt, const float* __restrict__ Wk,
    u16* __restrict__ dst, float* __restrict__ zz) {
  int id = blockIdx.x * 256 + threadIdx.x;
  if (blockIdx.x == 832) {
    if (threadIdx.x < 256) { zz[threadIdx.x] = 0.f; zz[256 + threadIdx.x] = 0.f; }
    return;
  }
  const float* src;
  int off, seg;
  if (id < 65536)       { src = Wq; off = 0;      seg = 65536; }
  else if (id < 131072) { src = Wv; off = 131072; seg = 65536; id -= 65536; }
  else if (id < 196608) { src = Wt; off = 262144; seg = 65536; id -= 131072; }
  else                  { src = Wk; off = 393216; seg = 16384; id -= 196608; }
  float v = src[id];
  u16 h = f2bf(v);
  u16 l = f2bf(v - bf2f(h));
  dst[off + id] = h;
  dst[off + seg + id] = l;
}

// ---------- transpose-convert: in fp32 [b][CIN][n] -> Thi/Tlo bf16 [b][n][CIN] ----------
template <int CIN>
__global__ __launch_bounds__(256) void tconv_kernel(
    const float* __restrict__ in, u16* __restrict__ Thi, u16* __restrict__ Tlo) {
  __shared__ float t[32][33];
  const int tid = threadIdx.x;
  const int b = blockIdx.x & 7, cg = blockIdx.x >> 3;
  const int c0 = cg << 5, n0 = blockIdx.y << 5;
  {
    int c = tid >> 3, m4 = (tid & 7) << 2;
    float4 v = *(const float4*)&in[((size_t)b * CIN + c0 + c) * SEQ + n0 + m4];
    t[c][m4 + 0] = v.x; t[c][m4 + 1] = v.y; t[c][m4 + 2] = v.z; t[c][m4 + 3] = v.w;
  }
  __syncthreads();
  {
    int n = tid >> 3, c4 = (tid & 7) << 2;
    u16 h[4], l[4];
#pragma unroll
    for (int j = 0; j < 4; ++j) {
      float v = t[c4 + j][n];
      h[j] = f2bf(v);
      l[j] = f2bf(v - bf2f(h[j]));
    }
    size_t base = ((size_t)b * SEQ + n0 + n) * CIN + c0 + c4;
    *(uint2*)&Thi[base] = make_uint2((unsigned)h[0] | ((unsigned)h[1] << 16),
                                     (unsigned)h[2] | ((unsigned)h[3] << 16));
    *(uint2*)&Tlo[base] = make_uint2((unsigned)l[0] | ((unsigned)l[1] << 16),
                                     (unsigned)l[2] | ((unsigned)l[3] << 16));
  }
}

// ---------- MFMA GEMM, hi/lo split (3-pass). act: [b][n][K] hi/lo; W: [256][K] hi/lo.
// WA=0: out bf16 [b][n][256]. WA=1: out [b][o][n] with row-stride `orows`, bf16 or fp32 (+bias).
// OUTF32 additionally accumulates BatchNorm partial sums into ssum/sqsum.
template <int K, bool WA, bool OUTF32>
__global__ __launch_bounds__(256) void gemm_kernel(
    const u16* __restrict__ Ahi, const u16* __restrict__ Alo,
    const u16* __restrict__ Whi, const u16* __restrict__ Wlo,
    const float* __restrict__ bias, void* __restrict__ outp,
    float* __restrict__ ssum, float* __restrict__ sqsum, int orows) {
  constexpr int SP = K + 8;
  extern __shared__ u16 lds[];  // 64*SP*2 shorts (hi rows then lo rows)
  static __shared__ float bsum[64], bsq[64];
  const int tid = threadIdx.x;
  const int wv = tid >> 6, lane = tid & 63, quad = lane >> 4, ln = lane & 15;
  const int b = blockIdx.x & 7, nt = blockIdx.x >> 3;
  const int o0 = blockIdx.y << 6, n0 = nt << 6;

  if (WA && OUTF32 && tid < 64) { bsum[tid] = 0.f; bsq[tid] = 0.f; }

  constexpr int RW = K / 8;
  for (int i = tid; i < 64 * RW; i += 256) {
    int row = i / RW, kc = (i % RW) * 8;
    *(uint4*)&lds[row * SP + kc] = *(const uint4*)&Whi[(size_t)(o0 + row) * K + kc];
    *(uint4*)&lds[(64 + row) * SP + kc] = *(const uint4*)&Wlo[(size_t)(o0 + row) * K + kc];
  }
  constexpr int NA = K / 32;
  bfrag8 ahi[NA], alo[NA];
  {
    const u16* ap = Ahi + ((size_t)b * SEQ + n0 + wv * 16 + ln) * K + quad * 8;
    const u16* al = Alo + ((size_t)b * SEQ + n0 + wv * 16 + ln) * K + quad * 8;
#pragma unroll
    for (int a = 0; a < NA; ++a) {
      ahi[a] = *(const bfrag8*)(ap + a * 32);
      alo[a] = *(const bfrag8*)(al + a * 32);
    }
  }
  __syncthreads();

  ffrag4 acc[4];
#pragma unroll
  for (int ot = 0; ot < 4; ++ot) {
    ffrag4 e = {0.f, 0.f, 0.f, 0.f};
#pragma unroll
    for (int a = 0; a < NA; ++a) {
      bfrag8 wh = *(const bfrag8*)&lds[(ot * 16 + ln) * SP + a * 32 + quad * 8];
      bfrag8 wl = *(const bfrag8*)&lds[(64 + ot * 16 + ln) * SP + a * 32 + quad * 8];
      if (WA) {
        e = MFMA16(wh, ahi[a], e);
        e = MFMA16(wh, alo[a], e);
        e = MFMA16(wl, ahi[a], e);
      } else {
        e = MFMA16(ahi[a], wh, e);
        e = MFMA16(alo[a], wh, e);
        e = MFMA16(ahi[a], wl, e);
      }
    }
    acc[ot] = e;
  }
  __syncthreads();  // lds free for epilogue

  if (!WA) {
    u16* tl = lds;  // [64 n][72]
#pragma unroll
    for (int ot = 0; ot < 4; ++ot)
#pragma unroll
      for (int r = 0; r < 4; ++r)
        tl[(wv * 16 + quad * 4 + r) * 72 + ot * 16 + ln] = f2bf(acc[ot][r]);
    __syncthreads();
    u16* out = (u16*)outp;
    for (int i = tid; i < 64 * 8; i += 256) {
      int row = i >> 3, c8 = (i & 7) * 8;
      *(uint4*)&out[((size_t)b * SEQ + n0 + row) * NC + o0 + c8] = *(uint4*)&tl[row * 72 + c8];
    }
  } else {
    float* fl = (float*)lds;  // [64 o][68]
#pragma unroll
    for (int ot = 0; ot < 4; ++ot)
#pragma unroll
      for (int r = 0; r < 4; ++r)
        fl[(ot * 16 + quad * 4 + r) * 68 + wv * 16 + ln] = acc[ot][r];
    __syncthreads();
    for (int i = tid; i < 64 * 16; i += 256) {
      int row = i >> 4, n4 = (i & 15) * 4;
      float bb = (bias != nullptr) ? bias[o0 + row] : 0.f;
      const float* src = &fl[row * 68 + n4];
      if (OUTF32) {
        float4 v = *(const float4*)src;
        v.x += bb; v.y += bb; v.z += bb; v.w += bb;
        *(float4*)&((float*)outp)[((size_t)b * orows + o0 + row) * SEQ + n0 + n4] = v;
        float s = v.x + v.y + v.z + v.w;
        float sq = v.x * v.x + v.y * v.y + v.z * v.z + v.w * v.w;
        atomicAdd(&bsum[row], s);
        atomicAdd(&bsq[row], sq);
      } else {
        uint2 pk;
        pk.x = (unsigned)f2bf(src[0] + bb) | ((unsigned)f2bf(src[1] + bb) << 16);
        pk.y = (unsigned)f2bf(src[2] + bb) | ((unsigned)f2bf(src[3] + bb) << 16);
        *(uint2*)&((u16*)outp)[((size_t)b * orows + o0 + row) * SEQ + n0 + n4] = pk;
      }
    }
    if (OUTF32) {
      __syncthreads();
      if (tid < 64) {
        atomicAdd(&ssum[o0 + tid], bsum[tid]);
        atomicAdd(&sqsum[o0 + tid], bsq[tid]);
      }
    }
  }
}

// ---------- energy: E computed ONCE. Writes expET[b][m][n] bf16, scales xv in place
// (xvp [b][272][n]; rows 0..255 *= rowinv[n], row 256 = rowinv[n]). ----------
__global__ __launch_bounds__(512, 4) void energy_kernel(
    const u16* __restrict__ xqT, const u16* __restrict__ xkT,
    u16* __restrict__ expET, u16* __restrict__ xvp) {
  __shared__ float rs_l[32];
  __shared__ float ri_l[32];
  const int tid = threadIdx.x;
  const int wv = tid >> 6, lane = tid & 63, quad = lane >> 4, ln = lane & 15;
  const int b = blockIdx.x & 7;
  const int n0 = (blockIdx.x >> 3) << 5;

  if (tid < 32) rs_l[tid] = 0.f;
  __syncthreads();

  // A-frags: 32 q rows (2 rowsets), K=256
  bfrag8 aq[2][8];
#pragma unroll
  for (int rs = 0; rs < 2; ++rs) {
    const u16* qp = xqT + ((size_t)b * SEQ + n0 + rs * 16 + ln) * NC + quad * 8;
#pragma unroll
    for (int kk = 0; kk < 8; ++kk) aq[rs][kk] = *(const bfrag8*)(qp + kk * 32);
  }

  // key B-frags: half-K ping-pong prefetch
  const u16* kbase = xkT + ((size_t)b * SEQ + (wv << 8) + ln) * NC + quad * 8;
  bfrag8 bkA[4], bkB[4];
#pragma unroll
  for (int kk = 0; kk < 4; ++kk) bkA[kk] = *(const bfrag8*)(kbase + kk * 32);

  float r0[4] = {0.f, 0.f, 0.f, 0.f}, r1[4] = {0.f, 0.f, 0.f, 0.f};
  for (int mt = 0; mt < 16; ++mt) {
    const u16* kcur = kbase + (size_t)mt * 16 * NC;
    const u16* knxt = kbase + (size_t)(mt + 1 < 16 ? mt + 1 : mt) * 16 * NC;
#pragma unroll
    for (int kk = 0; kk < 4; ++kk) bkB[kk] = *(const bfrag8*)(kcur + (4 + kk) * 32);
    ffrag4 e0 = {0.f, 0.f, 0.f, 0.f}, e1 = {0.f, 0.f, 0.f, 0.f};
#pragma unroll
    for (int kk = 0; kk < 4; ++kk) {
      e0 = MFMA16(aq[0][kk], bkA[kk], e0);
      e1 = MFMA16(aq[1][kk], bkA[kk], e1);
    }
#pragma unroll
    for (int kk = 0; kk < 4; ++kk) bkA[kk] = *(const bfrag8*)(knxt + kk * 32);
#pragma unroll
    for (int kk = 0; kk < 4; ++kk) {
      e0 = MFMA16(aq[0][4 + kk], bkB[kk], e0);
      e1 = MFMA16(aq[1][4 + kk], bkB[kk], e1);
    }
    const int m = (wv << 8) + (mt << 4) + ln;
    size_t ebase = ((size_t)b * SEQ + m) * SEQ + n0;
    float p0[4], p1[4];
#pragma unroll
    for (int r = 0; r < 4; ++r) {
      p0[r] = __expf(e0[r]); r0[r] += p0[r];
      p1[r] = __expf(e1[r]); r1[r] += p1[r];
    }
    *(uint2*)&expET[ebase + quad * 4] = make_uint2(
        (unsigned)f2bf(p0[0]) | ((unsigned)f2bf(p0[1]) << 16),
        (unsigned)f2bf(p0[2]) | ((unsigned)f2bf(p0[3]) << 16));
    *(uint2*)&expET[ebase + 16 + quad * 4] = make_uint2(
        (unsigned)f2bf(p1[0]) | ((unsigned)f2bf(p1[1]) << 16),
        (unsigned)f2bf(p1[2]) | ((unsigned)f2bf(p1[3]) << 16));
  }

  // reduce rowsums across ln within quads, combine across waves via LDS atomics
#pragma unroll
  for (int msk = 1; msk < 16; msk <<= 1) {
#pragma unroll
    for (int r = 0; r < 4; ++r) {
      r0[r] += __shfl_xor(r0[r], msk, 64);
      r1[r] += __shfl_xor(r1[r], msk, 64);
    }
  }
  if (ln == 0) {
#pragma unroll
    for (int r = 0; r < 4; ++r) {
      atomicAdd(&rs_l[quad * 4 + r], r0[r]);
      atomicAdd(&rs_l[16 + quad * 4 + r], r1[r]);
    }
  }
  __syncthreads();
  if (tid < 32) ri_l[tid] = 1.0f / rs_l[tid];
  __syncthreads();

  // epilogue: in-place scale of xv for this n-tile; row 256 = rowinv
  {
    const int c = tid >> 1, h = (tid & 1) << 4;
    u16* vp = xvp + ((size_t)b * 272 + c) * SEQ + n0 + h;
    uint4 a = *(const uint4*)vp;
    uint4 bq = *(const uint4*)(vp + 8);
    u16* pa = (u16*)&a;
    u16* pb = (u16*)&bq;
    u16 oa[8], ob[8];
#pragma unroll
    for (int j = 0; j < 8; ++j) {
      oa[j] = f2bf(bf2f(pa[j]) * ri_l[h + j]);
      ob[j] = f2bf(bf2f(pb[j]) * ri_l[h + 8 + j]);
    }
    *(uint4*)vp = *(uint4*)oa;
    *(uint4*)(vp + 8) = *(uint4*)ob;
  }
  if (tid < 32) xvp[((size_t)b * 272 + 256) * SEQ + n0 + tid] = f2bf(ri_l[tid]);
}

// ---------- pv: xrT_hi/lo[b][m][c] = bf16-split of U[c,m]/(1e-9+colsum[m]).
// U = xv'·expET (K=2048, LDS double-buffered B tiles, 1 barrier/chunk).
// Wave 7 additionally carries the rowinv row (c=256) whose output row 0 is colsum. ----------
__global__ __launch_bounds__(512, 4) void pv_kernel(
    const u16* __restrict__ expET, const u16* __restrict__ xvp,
    u16* __restrict__ xrT_hi, u16* __restrict__ xrT_lo) {
  __shared__ u16 bl[2][32 * 132];  // 32 m-rows x 128 k, stride 132 (bank-safe)
  __shared__ float cs_l[32];
  const int tid = threadIdx.x;
  const int wv = tid >> 6, lane = tid & 63, quad = lane >> 4, ln = lane & 15;
  const int b = blockIdx.x & 7;
  const int m0 = (blockIdx.x >> 3) << 5;

  const int srow = tid >> 4, sseg = tid & 15;
  const u16* gsrc = expET + ((size_t)b * SEQ + m0 + srow) * SEQ + sseg * 8;

  ffrag4 acc[2][2];  // [csub][msub]
#pragma unroll
  for (int i = 0; i < 2; ++i)
#pragma unroll
    for (int j = 0; j < 2; ++j) acc[i][j] = (ffrag4){0.f, 0.f, 0.f, 0.f};
  ffrag4 acs[2] = {{0.f, 0.f, 0.f, 0.f}, {0.f, 0.f, 0.f, 0.f}};

  uint4 pf = *(const uint4*)gsrc;
  const u16* abase = xvp + ((size_t)b * 272 + wv * 32 + ln) * SEQ + quad * 8;
  const u16* csbase = xvp + ((size_t)b * 272 + 256 + ln) * SEQ + quad * 8;

  for (int ch = 0; ch < 16; ++ch) {
    *(uint4*)&bl[ch & 1][srow * 132 + sseg * 8] = pf;
    const int chn = (ch + 1 < 16) ? ch + 1 : ch;
    pf = *(const uint4*)(gsrc + (size_t)chn * 128);
    __syncthreads();
    const u16* blc = &bl[ch & 1][0];
#pragma unroll
    for (int ks = 0; ks < 4; ++ks) {
      const int kg = ch * 128 + ks * 32;
      bfrag8 a0 = *(const bfrag8*)(abase + kg);
      bfrag8 a1 = *(const bfrag8*)(abase + 16 * SEQ + kg);
      bfrag8 b0 = *(const bfrag8*)&blc[ln * 132 + ks * 32 + quad * 8];
      bfrag8 b1 = *(const bfrag8*)&blc[(16 + ln) * 132 + ks * 32 + quad * 8];
      acc[0][0] = MFMA16(a0, b0, acc[0][0]);
      acc[0][1] = MFMA16(a0, b1, acc[0][1]);
      acc[1][0] = MFMA16(a1, b0, acc[1][0]);
      acc[1][1] = MFMA16(a1, b1, acc[1][1]);
      if (wv == 7) {
        bfrag8 ac = *(const bfrag8*)(csbase + kg);
        acs[0] = MFMA16(ac, b0, acs[0]);
        acs[1] = MFMA16(ac, b1, acs[1]);
      }
    }
  }

  if (wv == 7 && quad == 0) {
    cs_l[ln] = acs[0][0];
    cs_l[16 + ln] = acs[1][0];
  }
  __syncthreads();

#pragma unroll
  for (int ms = 0; ms < 2; ++ms) {
    const int m = m0 + ms * 16 + ln;
    float ic = 1.0f / (1e-9f + cs_l[ms * 16 + ln]);
#pragma unroll
    for (int cs2 = 0; cs2 < 2; ++cs2) {
      const int c = wv * 32 + cs2 * 16 + quad * 4;
      size_t obase = ((size_t)b * SEQ + m) * NC + c;
      u16 h[4], l[4];
#pragma unroll
      for (int r = 0; r < 4; ++r) {
        float v = acc[cs2][ms][r] * ic;
        h[r] = f2bf(v);
        l[r] = f2bf(v - bf2f(h[r]));
      }
      *(uint2*)&xrT_hi[obase] = make_uint2((unsigned)h[0] | ((unsigned)h[1] << 16),
                                           (unsigned)h[2] | ((unsigned)h[3] << 16));
      *(uint2*)&xrT_lo[obase] = make_uint2((unsigned)l[0] | ((unsigned)l[1] << 16),
                                           (unsigned)l[2] | ((unsigned)l[3] << 16));
    }
  }
}

// ---------- BN normalize + ReLU ----------
__global__ __launch_bounds__(256) void bnorm_kernel(
    const float* __restrict__ y, const float* __restrict__ ssum, const float* __restrict__ sqsum,
    const float* __restrict__ gamma, const float* __restrict__ beta, float* __restrict__ out) {
  size_t e0 = ((size_t)blockIdx.x * 256 + threadIdx.x) * 4;
  int o = (int)((e0 >> 11) & (NC - 1));
  const float invn = 1.0f / 16384.0f;
  float mean = ssum[o] * invn;
  float var = sqsum[o] * invn - mean * mean;
  float rs = rsqrtf(var + 1e-5f);
  float a = gamma[o] * rs;
  float c = beta[o] - mean * a;
  float4 v = *(const float4*)(y + e0);
  float4 r;
  r.x = fmaxf(0.f, fmaf(v.x, a, c));
  r.y = fmaxf(0.f, fmaf(v.y, a, c));
  r.z = fmaxf(0.f, fmaf(v.z, a, c));
  r.w = fmaxf(0.f, fmaf(v.w, a, c));
  *(float4*)(out + e0) = r;
}

extern "C" void kernel_launch(void* const* d_in, const int* in_sizes, int n_in,
                              void* d_out, int out_size, void* d_ws, size_t ws_size,
                              hipStream_t stream) {
  const float* q     = (const float*)d_in[0];
  const float* x     = (const float*)d_in[1];
  const float* Wq    = (const float*)d_in[2];
  const float* Wk    = (const float*)d_in[3];
  const float* Wv    = (const float*)d_in[4];
  const float* bv    = (const float*)d_in[5];
  const float* Wt    = (const float*)d_in[6];
  const float* bt    = (const float*)d_in[7];
  const float* gamma = (const float*)d_in[8];
  const float* beta  = (const float*)d_in[9];
  float* out = (float*)d_out;

  // Arena (phase-overlaid), ~115 MB total:
  // [0,64M):   expET bf16 [B][M][N]  -> later y fp32 [B][C][N] at [0,16M)
  // [64,80M):  qT hi/lo              -> later xrT hi/lo
  // [80,84M):  xT hi/lo
  // [84,92M):  xqT bf16 [B][N][C]
  // [92,100M): xkT bf16 [B][M][C]
  // [100,109M): xvp bf16 [B][272][N] (gemm writes rows 0..255; energy scales in place)
  // [109M+):   wpack (852 KB) + ssum/sqsum
  char* wsb = (char*)d_ws;
  u16* expET  = (u16*)wsb;
  float* y    = (float*)wsb;
  u16* qT_hi  = (u16*)(wsb + 64 * MB_);
  u16* qT_lo  = (u16*)(wsb + 72 * MB_);
  u16* xrT_hi = qT_hi;
  u16* xrT_lo = qT_lo;
  u16* xT_hi  = (u16*)(wsb + 80 * MB_);
  u16* xT_lo  = (u16*)(wsb + 82 * MB_);
  u16* xqT    = (u16*)(wsb + 84 * MB_);
  u16* xkT    = (u16*)(wsb + 92 * MB_);
  u16* xvp    = (u16*)(wsb + 100 * MB_);
  u16* wpack  = (u16*)(wsb + 109 * MB_);
  u16* Wq_hi = wpack,          *Wq_lo = wpack + 65536;
  u16* Wv_hi = wpack + 131072, *Wv_lo = wpack + 196608;
  u16* Wt_hi = wpack + 262144, *Wt_lo = wpack + 327680;
  u16* Wk_hi = wpack + 393216, *Wk_lo = wpack + 409600;
  float* ssum  = (float*)(wsb + 109 * MB_ + 852 * 1024);
  float* sqsum = ssum + NC;

  wconv_kernel<<<833, 256, 0, stream>>>(Wq, Wv, Wt, Wk, wpack, ssum);
  tconv_kernel<NC><<<dim3(64, 64), 256, 0, stream>>>(q, qT_hi, qT_lo);
  tconv_kernel<NCK><<<dim3(16, 64), 256, 0, stream>>>(x, xT_hi, xT_lo);

  const size_t shm256 = 64 * (256 + 8) * 2 * sizeof(u16);  // 67,584 B
  const size_t shm64  = 64 * (64 + 8) * 2 * sizeof(u16);   // 18,432 B
  gemm_kernel<256, false, false><<<dim3(256, 4), 256, shm256, stream>>>(
      qT_hi, qT_lo, Wq_hi, Wq_lo, nullptr, xqT, nullptr, nullptr, 256);
  gemm_kernel<64, false, false><<<dim3(256, 4), 256, shm64, stream>>>(
      xT_hi, xT_lo, Wk_hi, Wk_lo, nullptr, xkT, nullptr, nullptr, 256);
  gemm_kernel<256, true, false><<<dim3(256, 4), 256, shm256, stream>>>(
      qT_hi, qT_lo, Wv_hi, Wv_lo, bv, xvp, nullptr, nullptr, 272);

  energy_kernel<<<512, 512, 0, stream>>>(xqT, xkT, expET, xvp);
  pv_kernel<<<512, 512, 0, stream>>>(expET, xvp, xrT_hi, xrT_lo);

  gemm_kernel<256, true, true><<<dim3(256, 4), 256, shm256, stream>>>(
      xrT_hi, xrT_lo, Wt_hi, Wt_lo, bt, y, ssum, sqsum, 256);

  bnorm_kernel<<<4096, 256, 0, stream>>>(y, ssum, sqsum, gamma, beta, out);
}